// Round 10
// baseline (104.860 us; speedup 1.0000x reference)
//
#include <hip/hip_runtime.h>

#define BN 4
#define CN 256
#define PN 4096
#define QT 32
#define TSTR 264

typedef __attribute__((ext_vector_type(8))) short short8;
typedef __attribute__((ext_vector_type(8))) unsigned short ushort8;
typedef __attribute__((ext_vector_type(4))) float f32x4;
typedef __attribute__((ext_vector_type(4))) unsigned int u32x4;
typedef unsigned int u32;

__device__ __forceinline__ unsigned short f2bf(float f) {
  u32 u = __builtin_bit_cast(u32, f);
  return (unsigned short)((u + 0x7fffu + ((u >> 16) & 1u)) >> 16);
}

__device__ __forceinline__ void async_copy16(const void* g, void* l) {
  __builtin_amdgcn_global_load_lds((const __attribute__((address_space(1))) u32*)g,
                                   (__attribute__((address_space(3))) u32*)l, 16, 0, 0);
}

// Frag-major layout (per batch, per 64-q block = 32 KB = 32 frags of 1024B):
//   frag F = nt*8 + kc  (nt = q-sub-block of 16, kc = 32-ch chunk)
//   byte  = F*1024 + (g*16 + lr)*16 + j*2  <->  xn[q = qb*64 + nt*16 + lr][ch = kc*32 + g*8 + j]
// V layout same frag shape but PERMUTED q: frag f = kk*16 + n2 holds
//   byte = f*1024 + (g*16 + lr)*16 + j*2  <->  V[q = kk*32 + perm(g*8+j)][c = n2*16 + lr]
//   perm: q32 bits (q4..q0) = (k2, k4, k3, k1, k0) -- matches cvt_pk'd S word order.
// QT=32 tile t = 16KB slice [t*16384, t*16384+16K) of both arrays (pure linear DMA).

// ---- k_nx: channel norms + xnK (frag-major bf16)
__global__ __launch_bounds__(256) void k_nx(const float* __restrict__ x,
                                            float* __restrict__ mnorm,
                                            unsigned short* __restrict__ xnK) {
  __shared__ unsigned short tl[64 * TSTR];
  __shared__ float red[4][64];
  const int b = blockIdx.y, qb = blockIdx.x, p0 = qb * 64;
  const int tid = threadIdx.x;
  const int tp = tid & 63, cg = tid >> 6;
  const float* xp = x + ((size_t)b * CN + cg * 64) * PN + p0 + tp;
  float v[64];
  float ss = 0.f;
#pragma unroll
  for (int i = 0; i < 64; ++i) {
    v[i] = xp[(size_t)i * PN];
    ss += v[i] * v[i];
  }
  red[cg][tp] = ss;
  __syncthreads();
  float nrm = sqrtf(red[0][tp] + red[1][tp] + red[2][tp] + red[3][tp]);
  float mn = fmaxf(nrm, 1e-8f);
  float rn = 1.f / mn;
  if (cg == 0) mnorm[b * PN + p0 + tp] = mn;
  unsigned int* tl32 = (unsigned int*)tl;
#pragma unroll
  for (int j = 0; j < 32; ++j) {
    unsigned int w = (unsigned int)f2bf(v[2 * j] * rn) |
                     ((unsigned int)f2bf(v[2 * j + 1] * rn) << 16);
    tl32[tp * (TSTR / 2) + cg * 32 + j] = w;
  }
  __syncthreads();
  char* dstb = (char*)xnK + (size_t)b * (PN * CN * 2) + (size_t)qb * 32768;
#pragma unroll
  for (int m = 0; m < 8; ++m) {
    int idx = m * 256 + tid;
    int F = idx >> 6, ln = idx & 63;
    int pl = (F >> 3) * 16 + (ln & 15);
    int ch = (F & 7) * 32 + (ln >> 4) * 8;
    ushort8 o = *(const ushort8*)(tl + pl * TSTR + ch);
    *(ushort8*)(dstb + (size_t)idx * 16) = o;
  }
}

// ---- k_gx: gxF[b][qb][frag-major, q-permuted] = bf16((W@xn)*mnorm + bias)
__global__ void k_gx(const float* __restrict__ Wm, const float* __restrict__ bias,
                     const unsigned short* __restrict__ xnK, const float* __restrict__ mnorm,
                     unsigned short* __restrict__ gxF) {
  const int b = blockIdx.z;
  const int m0 = blockIdx.y * 64;
  const int qb = blockIdx.x, q0 = qb * 64;
  const int tid = threadIdx.x;
  const int wave = tid >> 6, lane = tid & 63;
  const int lr = lane & 15, g = lane >> 4;

  short8 af[8];
  {
    const float* wr = Wm + (size_t)(m0 + wave * 16 + lr) * CN;
#pragma unroll
    for (int k = 0; k < 8; ++k) {
      const float* ap = wr + k * 32 + g * 8;
      short8 a;
#pragma unroll
      for (int j = 0; j < 8; ++j) a[j] = (short)f2bf(ap[j]);
      af[k] = a;
    }
  }
  f32x4 acc[4];
#pragma unroll
  for (int n = 0; n < 4; ++n) acc[n] = (f32x4){0.f, 0.f, 0.f, 0.f};

  const char* xb = (const char*)xnK + (size_t)b * (PN * CN * 2) + (size_t)qb * 32768;
#pragma unroll
  for (int n = 0; n < 4; ++n)
#pragma unroll
    for (int k = 0; k < 8; ++k) {
      short8 bf = *(const short8*)(xb + ((n * 8 + k) << 10) + ((g * 16 + lr) << 4));
      acc[n] = __builtin_amdgcn_mfma_f32_16x16x32_bf16(af[k], bf, acc[n], 0, 0, 0);
    }
  char* vbb = (char*)gxF + (size_t)b * (PN * CN * 2) + (size_t)qb * 32768;
#pragma unroll
  for (int n = 0; n < 4; ++n) {
    int q = q0 + n * 16 + lr;
    float mn = mnorm[b * PN + q];
    int kk = n >> 1;
    int q32 = (n & 1) * 16 + lr;
    int gp = (q32 >> 2) & 3;
    int j = ((q32 >> 4) & 1) * 4 + (q32 & 3);
#pragma unroll
    for (int i = 0; i < 4; ++i) {
      int c = m0 + wave * 16 + g * 4 + i;
      float v = acc[n][i] * mn + bias[c];
      *(unsigned short*)(vbb + ((kk * 16 + (c >> 4)) << 10) + (gp << 8) + ((c & 15) << 4) + (j << 1)) = f2bf(v);
    }
  }
}

// ---- fused attention: 4-wave WG (256 thr), M=32 rows/wave (128/WG), QT=32,
// 64KB LDS dbuf -> 2 independent WGs/CU (decorrelated barrier domains).
// Linear DMA both sides; S entirely in registers (q-permuted cvt_pk pack).
extern __shared__ char smem[];

__global__ __launch_bounds__(256, 2) void k_attn(const unsigned short* __restrict__ xnK,
                                                 const unsigned short* __restrict__ gxF,
                                                 float* __restrict__ d0, float* __restrict__ d1,
                                                 float* __restrict__ d2, float* __restrict__ d3,
                                                 int lq, int ntiles) {
  const int fid = blockIdx.x;
  const int b = fid & 3;
  const int qs = (fid >> 2) & ((1 << lq) - 1);
  const int pblk = fid >> (2 + lq);
  const int tid = threadIdx.x;
  const int wave = tid >> 6, lane = tid & 63, lr = lane & 15, g = lane >> 4;
  const int p0 = pblk * 128 + wave * 32;
  float* dst = (qs == 0) ? d0 : (qs == 1) ? d1 : (qs == 2) ? d2 : d3;

  const char* xb = (const char*)xnK + (size_t)b * (PN * CN * 2);
  const char* vg = (const char*)gxF + (size_t)b * (PN * CN * 2);
  // q-range for this split starts at tile index qt0 (16KB granularity)
  const int qt0 = (qs * (PN >> lq)) >> 5;
  const char* kq = xb + (size_t)qt0 * 16384;
  const char* vq = vg + (size_t)qt0 * 16384;
  const int ldst = tid * 16;
  const int lane16 = lane * 16;

  auto issue_K = [&](int t) {
    char* kb = smem + (t & 1) * 32768;
    const char* s = kq + (size_t)t * 16384 + ldst;
#pragma unroll
    for (int j = 0; j < 4; ++j) async_copy16(s + j * 4096, kb + ldst + j * 4096);
  };
  auto issue_V = [&](int t) {
    char* vb = smem + (t & 1) * 32768 + 16384;
    const char* s = vq + (size_t)t * 16384 + ldst;
#pragma unroll
    for (int j = 0; j < 4; ++j) async_copy16(s + j * 4096, vb + ldst + j * 4096);
  };

  issue_K(0);
  issue_V(0);

  // Q hoist from frag-major xnK (128 rows/WG = 2 qb-blocks; wave>>1 picks block)
  short8 qf[2][8];
  {
    const char* qpb = xb + (size_t)(pblk * 2 + (wave >> 1)) * 32768;
#pragma unroll
    for (int mt = 0; mt < 2; ++mt) {
      int ntp = (wave & 1) * 2 + mt;
#pragma unroll
      for (int k = 0; k < 8; ++k)
        qf[mt][k] = *(const short8*)(qpb + ((ntp * 8 + k) << 10) + ((g * 16 + lr) << 4));
    }
  }

  f32x4 yacc[2][16];
#pragma unroll
  for (int mt = 0; mt < 2; ++mt)
#pragma unroll
    for (int n = 0; n < 16; ++n) yacc[mt][n] = (f32x4){0.f, 0.f, 0.f, 0.f};

  for (int t = 0; t < ntiles; ++t) {
    const char* kb = smem + (t & 1) * 32768;
    const char* vb = kb + 16384;

    asm volatile("s_waitcnt vmcnt(4)" ::: "memory");  // K(t) ready (V(t) in flight)
    __builtin_amdgcn_s_barrier();
    if (t + 1 < ntiles) { issue_K(t + 1); issue_V(t + 1); }

    // QKT (swapped: D[q][p] = mfma(K, Q)), 32 MFMA; S packed in registers
    f32x4 sacc[2][2];
#pragma unroll
    for (int n0 = 0; n0 < 2; ++n0)
#pragma unroll
      for (int mt = 0; mt < 2; ++mt) sacc[n0][mt] = (f32x4){0.f, 0.f, 0.f, 0.f};
    __builtin_amdgcn_s_setprio(1);
#pragma unroll
    for (int k = 0; k < 8; ++k) {
      short8 kf0 = *(const short8*)(kb + k * 1024 + lane16);
      short8 kf1 = *(const short8*)(kb + (8 + k) * 1024 + lane16);
      sacc[0][0] = __builtin_amdgcn_mfma_f32_16x16x32_bf16(kf0, qf[0][k], sacc[0][0], 0, 0, 0);
      sacc[0][1] = __builtin_amdgcn_mfma_f32_16x16x32_bf16(kf0, qf[1][k], sacc[0][1], 0, 0, 0);
      sacc[1][0] = __builtin_amdgcn_mfma_f32_16x16x32_bf16(kf1, qf[0][k], sacc[1][0], 0, 0, 0);
      sacc[1][1] = __builtin_amdgcn_mfma_f32_16x16x32_bf16(kf1, qf[1][k], sacc[1][1], 0, 0, 0);
    }
    __builtin_amdgcn_s_setprio(0);

    // relu^2 -> q-permuted cvt_pk pack (S stays in registers)
    u32 pa[2][4];
#pragma unroll
    for (int mt = 0; mt < 2; ++mt)
#pragma unroll
      for (int n0 = 0; n0 < 2; ++n0)
#pragma unroll
        for (int h = 0; h < 2; ++h) {
          float a0 = fmaxf(sacc[n0][mt][2 * h], 0.f);
          a0 *= a0;
          float a1 = fmaxf(sacc[n0][mt][2 * h + 1], 0.f);
          a1 *= a1;
          u32 w;
          asm("v_cvt_pk_bf16_f32 %0, %1, %2" : "=v"(w) : "v"(a0), "v"(a1));
          pa[mt][n0 * 2 + h] = w;
        }

    if (t + 1 < ntiles) {
      asm volatile("s_waitcnt vmcnt(8)" ::: "memory");  // V(t) ready (t+1 in flight)
    } else {
      asm volatile("s_waitcnt vmcnt(0)" ::: "memory");
    }
    __builtin_amdgcn_s_barrier();

    // PV: Y[32p][256c] += S[32p x 32q] @ V[32q x 256c] (shared q-permutation)
    u32x4 w0 = {pa[0][0], pa[0][1], pa[0][2], pa[0][3]};
    u32x4 w1 = {pa[1][0], pa[1][1], pa[1][2], pa[1][3]};
    short8 a0 = __builtin_bit_cast(short8, w0);
    short8 a1 = __builtin_bit_cast(short8, w1);
    __builtin_amdgcn_s_setprio(1);
#pragma unroll
    for (int n2 = 0; n2 < 16; ++n2) {
      short8 vf = *(const short8*)(vb + n2 * 1024 + lane16);
      yacc[0][n2] = __builtin_amdgcn_mfma_f32_16x16x32_bf16(a0, vf, yacc[0][n2], 0, 0, 0);
      yacc[1][n2] = __builtin_amdgcn_mfma_f32_16x16x32_bf16(a1, vf, yacc[1][n2], 0, 0, 0);
    }
    __builtin_amdgcn_s_setprio(0);
  }
  __builtin_amdgcn_s_barrier();

  // ---- epilogue: per-wave LDS transpose (16KB each) for coalesced [c][p] stores
  // yacc[mt][n2][i] = y[p = p0 + mt*16 + g*4+i][c = n2*16 + lr]
  float* yl = (float*)(smem + wave * 16384);
  const int row8 = lane >> 3, p4 = (lane & 7) << 2;
#pragma unroll
  for (int cc = 0; cc < 4; ++cc) {
#pragma unroll
    for (int nn = 0; nn < 4; ++nn)
#pragma unroll
      for (int mt = 0; mt < 2; ++mt)
#pragma unroll
        for (int i = 0; i < 4; ++i)
          yl[(nn * 16 + lr) * 33 + mt * 16 + g * 4 + i] = yacc[mt][cc * 4 + nn][i];
#pragma unroll
    for (int r2 = 0; r2 < 8; ++r2) {
      int c = r2 * 8 + row8;
      float4 v = *(const float4*)(yl + c * 33 + p4);
      *(float4*)(dst + ((size_t)b * CN + cc * 64 + c) * PN + p0 + p4) = v;
    }
  }
}

// ---- final reduction: out += sum of partials
__global__ void k_add(float* __restrict__ o, const float* __restrict__ a,
                      const float* __restrict__ bb, const float* __restrict__ c,
                      int np, int n4) {
  int i = blockIdx.x * blockDim.x + threadIdx.x;
  int stride = gridDim.x * blockDim.x;
  float4* o4 = (float4*)o;
  const float4* a4 = (const float4*)a;
  const float4* b4 = (const float4*)bb;
  const float4* c4 = (const float4*)c;
  for (; i < n4; i += stride) {
    float4 r = o4[i];
    float4 va = a4[i];
    r.x += va.x; r.y += va.y; r.z += va.z; r.w += va.w;
    if (np > 1) {
      float4 vb = b4[i];
      r.x += vb.x; r.y += vb.y; r.z += vb.z; r.w += vb.w;
      float4 vc = c4[i];
      r.x += vc.x; r.y += vc.y; r.z += vc.z; r.w += vc.w;
    }
    o4[i] = r;
  }
}

extern "C" void kernel_launch(void* const* d_in, const int* in_sizes, int n_in,
                              void* d_out, int out_size, void* d_ws, size_t ws_size,
                              hipStream_t stream) {
  const float* x = (const float*)d_in[0];
  const float* Wm = (const float*)d_in[1];
  const float* bias = (const float*)d_in[2];
  float* out = (float*)d_out;

  char* ws = (char*)d_ws;
  unsigned short* xnK = (unsigned short*)ws;                        // 8 MB  frag-major xn
  unsigned short* gxF = (unsigned short*)(ws + (size_t)8388608);    // 8 MB  frag-major permuted V
  float* mnorm = (float*)(ws + (size_t)16777216);                   // 64 KB [B][P] f32
  float* yp0 = (float*)(ws + (size_t)16842752);                     // 16 MB partials x3
  float* yp1 = yp0 + 4194304;
  float* yp2 = yp1 + 4194304;
  const size_t need4 = 16842752ULL + 3ULL * 16777216ULL;

  hipFuncSetAttribute(reinterpret_cast<const void*>(k_attn),
                      hipFuncAttributeMaxDynamicSharedMemorySize, 65536);

  k_nx<<<dim3(PN / 64, BN), 256, 0, stream>>>(x, mnorm, xnK);
  k_gx<<<dim3(PN / 64, CN / 64, BN), 256, 0, stream>>>(Wm, bias, xnK, mnorm, gxF);
  if (ws_size >= need4) {
    k_attn<<<dim3(512), 256, 65536, stream>>>(xnK, gxF, out, yp0, yp1, yp2, 2, (PN / 4) / QT);
    k_add<<<dim3(1024), 256, 0, stream>>>(out, yp0, yp1, yp2, 3, BN * CN * PN / 4);
  } else {
    k_attn<<<dim3(256), 256, 65536, stream>>>(xnK, gxF, out, yp0, yp0, yp0, 1, (PN / 2) / QT);
    k_add<<<dim3(1024), 256, 0, stream>>>(out, yp0, yp0, yp0, 1, BN * CN * PN / 4);
  }
}

// Round 11
// 104.259 us; speedup vs baseline: 1.0058x; 1.0058x over previous
//
#include <hip/hip_runtime.h>
#include <hip/hip_fp16.h>

#define BN 4
#define CN 256
#define PN 4096
#define QT 32
#define TSTR 264

typedef __attribute__((ext_vector_type(8))) short short8;
typedef __attribute__((ext_vector_type(8))) unsigned short ushort8;
typedef __attribute__((ext_vector_type(4))) unsigned short us4;
typedef __attribute__((ext_vector_type(4))) float f32x4;
typedef __attribute__((ext_vector_type(4))) unsigned int u32x4;
typedef unsigned int u32;

__device__ __forceinline__ unsigned short f2bf(float f) {
  u32 u = __builtin_bit_cast(u32, f);
  return (unsigned short)((u + 0x7fffu + ((u >> 16) & 1u)) >> 16);
}

__device__ __forceinline__ void async_copy16(const void* g, void* l) {
  __builtin_amdgcn_global_load_lds((const __attribute__((address_space(1))) u32*)g,
                                   (__attribute__((address_space(3))) u32*)l, 16, 0, 0);
}

// Frag-major layout (per batch, per 64-q block = 32 KB = 32 frags of 1024B):
//   frag F = nt*8 + kc; byte = F*1024 + (g*16+lr)*16 + j*2
//     <-> xn[q = qb*64 + nt*16 + lr][ch = kc*32 + g*8 + j]
// V frags q-PERMUTED: frag f = kk*16 + n2; byte = f*1024 + (g*16+lr)*16 + j*2
//     <-> V[q = kk*32 + perm(g*8+j)][c = n2*16 + lr]
// QT=32 tile t = 16KB slice [t*16384, +16K) of both arrays (pure linear DMA).

// ---- k_nx: channel norms + xnK (frag-major bf16)
__global__ __launch_bounds__(256) void k_nx(const float* __restrict__ x,
                                            float* __restrict__ mnorm,
                                            unsigned short* __restrict__ xnK) {
  __shared__ unsigned short tl[64 * TSTR];
  __shared__ float red[4][64];
  const int b = blockIdx.y, qb = blockIdx.x, p0 = qb * 64;
  const int tid = threadIdx.x;
  const int tp = tid & 63, cg = tid >> 6;
  const float* xp = x + ((size_t)b * CN + cg * 64) * PN + p0 + tp;
  float v[64];
  float ss = 0.f;
#pragma unroll
  for (int i = 0; i < 64; ++i) {
    v[i] = xp[(size_t)i * PN];
    ss += v[i] * v[i];
  }
  red[cg][tp] = ss;
  __syncthreads();
  float nrm = sqrtf(red[0][tp] + red[1][tp] + red[2][tp] + red[3][tp]);
  float mn = fmaxf(nrm, 1e-8f);
  float rn = 1.f / mn;
  if (cg == 0) mnorm[b * PN + p0 + tp] = mn;
  unsigned int* tl32 = (unsigned int*)tl;
#pragma unroll
  for (int j = 0; j < 32; ++j) {
    unsigned int w = (unsigned int)f2bf(v[2 * j] * rn) |
                     ((unsigned int)f2bf(v[2 * j + 1] * rn) << 16);
    tl32[tp * (TSTR / 2) + cg * 32 + j] = w;
  }
  __syncthreads();
  char* dstb = (char*)xnK + (size_t)b * (PN * CN * 2) + (size_t)qb * 32768;
#pragma unroll
  for (int m = 0; m < 8; ++m) {
    int idx = m * 256 + tid;
    int F = idx >> 6, ln = idx & 63;
    int pl = (F >> 3) * 16 + (ln & 15);
    int ch = (F & 7) * 32 + (ln >> 4) * 8;
    ushort8 o = *(const ushort8*)(tl + pl * TSTR + ch);
    *(ushort8*)(dstb + (size_t)idx * 16) = o;
  }
}

// ---- k_gx: gxF[b][qb][frag-major, q-permuted] = bf16((W@xn)*mnorm + bias)
__global__ void k_gx(const float* __restrict__ Wm, const float* __restrict__ bias,
                     const unsigned short* __restrict__ xnK, const float* __restrict__ mnorm,
                     unsigned short* __restrict__ gxF) {
  const int b = blockIdx.z;
  const int m0 = blockIdx.y * 64;
  const int qb = blockIdx.x, q0 = qb * 64;
  const int tid = threadIdx.x;
  const int wave = tid >> 6, lane = tid & 63;
  const int lr = lane & 15, g = lane >> 4;

  short8 af[8];
  {
    const float* wr = Wm + (size_t)(m0 + wave * 16 + lr) * CN;
#pragma unroll
    for (int k = 0; k < 8; ++k) {
      const float* ap = wr + k * 32 + g * 8;
      short8 a;
#pragma unroll
      for (int j = 0; j < 8; ++j) a[j] = (short)f2bf(ap[j]);
      af[k] = a;
    }
  }
  f32x4 acc[4];
#pragma unroll
  for (int n = 0; n < 4; ++n) acc[n] = (f32x4){0.f, 0.f, 0.f, 0.f};

  const char* xb = (const char*)xnK + (size_t)b * (PN * CN * 2) + (size_t)qb * 32768;
#pragma unroll
  for (int n = 0; n < 4; ++n)
#pragma unroll
    for (int k = 0; k < 8; ++k) {
      short8 bf = *(const short8*)(xb + ((n * 8 + k) << 10) + ((g * 16 + lr) << 4));
      acc[n] = __builtin_amdgcn_mfma_f32_16x16x32_bf16(af[k], bf, acc[n], 0, 0, 0);
    }
  char* vbb = (char*)gxF + (size_t)b * (PN * CN * 2) + (size_t)qb * 32768;
#pragma unroll
  for (int n = 0; n < 4; ++n) {
    int q = q0 + n * 16 + lr;
    float mn = mnorm[b * PN + q];
    int kk = n >> 1;
    int q32 = (n & 1) * 16 + lr;
    int gp = (q32 >> 2) & 3;
    int j = ((q32 >> 4) & 1) * 4 + (q32 & 3);
#pragma unroll
    for (int i = 0; i < 4; ++i) {
      int c = m0 + wave * 16 + g * 4 + i;
      float v = acc[n][i] * mn + bias[c];
      *(unsigned short*)(vbb + ((kk * 16 + (c >> 4)) << 10) + (gp << 8) + ((c & 15) << 4) + (j << 1)) = f2bf(v);
    }
  }
}

// ---- fused attention: 8-wave WG, M=32/wave (256 rows/WG), QT=32, TRIPLE-buffered
// K/V tiles (3 x 32KB = 96KB LDS, 1 WG/CU, 2 waves/SIMD). Tile t's body interleaves
// QKT(t) with PV(t-1) (pa + V(t-1) both live) -> 2 independent MFMA streams/wave.
// One vmcnt(2)+barrier per tile: covers {K(t),V(t-1)} landed, V(t) in flight.
extern __shared__ char smem[];

__global__ __launch_bounds__(512, 2) void k_attn(const unsigned short* __restrict__ xnK,
                                                 const unsigned short* __restrict__ gxF,
                                                 float* __restrict__ out,
                                                 __half* __restrict__ p1, __half* __restrict__ p2,
                                                 __half* __restrict__ p3,
                                                 int lq, int ntiles) {
  const int fid = blockIdx.x;
  const int b = fid & 3;
  const int qs = (fid >> 2) & ((1 << lq) - 1);
  const int pblk = fid >> (2 + lq);
  const int tid = threadIdx.x;
  const int wave = tid >> 6, lane = tid & 63, lr = lane & 15, g = lane >> 4;
  const int p0 = pblk * 256 + wave * 32;
  __half* dsth = (qs == 1) ? p1 : (qs == 2) ? p2 : p3;

  const char* xb = (const char*)xnK + (size_t)b * (PN * CN * 2);
  const char* vgb = (const char*)gxF + (size_t)b * (PN * CN * 2);
  const int qt0 = (qs * (PN >> lq)) >> 5;
  const char* kq = xb + (size_t)qt0 * 16384;
  const char* vq = vgb + (size_t)qt0 * 16384;
  const int ldst = tid * 16;
  const int lane16 = lane * 16;

  auto issue = [&](int t) {
    char* buf = smem + (t % 3) * 32768;
    const char* ks = kq + (size_t)t * 16384 + ldst;
    const char* vs = vq + (size_t)t * 16384 + ldst;
    async_copy16(ks, buf + ldst);
    async_copy16(ks + 8192, buf + ldst + 8192);
    async_copy16(vs, buf + 16384 + ldst);
    async_copy16(vs + 8192, buf + 16384 + ldst + 8192);
  };

  issue(0);

  // Q hoist (32 p-rows x 256 ch as B-operand frags)
  short8 qf[2][8];
  {
    const char* qpb = xb + (size_t)(pblk * 4 + (wave >> 1)) * 32768;
#pragma unroll
    for (int mt = 0; mt < 2; ++mt) {
      int ntp = (wave & 1) * 2 + mt;
#pragma unroll
      for (int k = 0; k < 8; ++k)
        qf[mt][k] = *(const short8*)(qpb + ((ntp * 8 + k) << 10) + ((g * 16 + lr) << 4));
    }
  }

  f32x4 yacc[2][16];
#pragma unroll
  for (int mt = 0; mt < 2; ++mt)
#pragma unroll
    for (int n = 0; n < 16; ++n) yacc[mt][n] = (f32x4){0.f, 0.f, 0.f, 0.f};

  u32 pa[2][4];

  // ---- tile 0: QKT only
  {
    const char* kb = smem;
    asm volatile("s_waitcnt vmcnt(2)" ::: "memory");
    __builtin_amdgcn_s_barrier();
    issue(1);
    f32x4 sacc[2][2];
#pragma unroll
    for (int n0 = 0; n0 < 2; ++n0)
#pragma unroll
      for (int mt = 0; mt < 2; ++mt) sacc[n0][mt] = (f32x4){0.f, 0.f, 0.f, 0.f};
    __builtin_amdgcn_s_setprio(1);
#pragma unroll
    for (int k = 0; k < 8; ++k) {
      short8 kf0 = *(const short8*)(kb + k * 1024 + lane16);
      short8 kf1 = *(const short8*)(kb + (8 + k) * 1024 + lane16);
      sacc[0][0] = __builtin_amdgcn_mfma_f32_16x16x32_bf16(kf0, qf[0][k], sacc[0][0], 0, 0, 0);
      sacc[0][1] = __builtin_amdgcn_mfma_f32_16x16x32_bf16(kf0, qf[1][k], sacc[0][1], 0, 0, 0);
      sacc[1][0] = __builtin_amdgcn_mfma_f32_16x16x32_bf16(kf1, qf[0][k], sacc[1][0], 0, 0, 0);
      sacc[1][1] = __builtin_amdgcn_mfma_f32_16x16x32_bf16(kf1, qf[1][k], sacc[1][1], 0, 0, 0);
    }
    __builtin_amdgcn_s_setprio(0);
#pragma unroll
    for (int mt = 0; mt < 2; ++mt)
#pragma unroll
      for (int n0 = 0; n0 < 2; ++n0)
#pragma unroll
        for (int h = 0; h < 2; ++h) {
          float a0 = fmaxf(sacc[n0][mt][2 * h], 0.f); a0 *= a0;
          float a1 = fmaxf(sacc[n0][mt][2 * h + 1], 0.f); a1 *= a1;
          u32 w;
          asm("v_cvt_pk_bf16_f32 %0, %1, %2" : "=v"(w) : "v"(a0), "v"(a1));
          pa[mt][n0 * 2 + h] = w;
        }
  }

  // ---- main loop: tile t interleaves QKT(t) with PV(t-1)
  for (int t = 1; t < ntiles; ++t) {
    const char* kb = smem + (t % 3) * 32768;
    const char* vbp = smem + ((t + 2) % 3) * 32768 + 16384;
    asm volatile("s_waitcnt vmcnt(2)" ::: "memory");
    __builtin_amdgcn_s_barrier();
    if (t + 1 < ntiles) issue(t + 1);

    u32x4 w0 = {pa[0][0], pa[0][1], pa[0][2], pa[0][3]};
    u32x4 w1 = {pa[1][0], pa[1][1], pa[1][2], pa[1][3]};
    short8 a0 = __builtin_bit_cast(short8, w0);
    short8 a1 = __builtin_bit_cast(short8, w1);

    f32x4 sacc[2][2];
#pragma unroll
    for (int n0 = 0; n0 < 2; ++n0)
#pragma unroll
      for (int mt = 0; mt < 2; ++mt) sacc[n0][mt] = (f32x4){0.f, 0.f, 0.f, 0.f};
    __builtin_amdgcn_s_setprio(1);
#pragma unroll
    for (int k = 0; k < 8; ++k) {
      short8 kf0 = *(const short8*)(kb + k * 1024 + lane16);
      short8 kf1 = *(const short8*)(kb + (8 + k) * 1024 + lane16);
      sacc[0][0] = __builtin_amdgcn_mfma_f32_16x16x32_bf16(kf0, qf[0][k], sacc[0][0], 0, 0, 0);
      sacc[0][1] = __builtin_amdgcn_mfma_f32_16x16x32_bf16(kf0, qf[1][k], sacc[0][1], 0, 0, 0);
      sacc[1][0] = __builtin_amdgcn_mfma_f32_16x16x32_bf16(kf1, qf[0][k], sacc[1][0], 0, 0, 0);
      sacc[1][1] = __builtin_amdgcn_mfma_f32_16x16x32_bf16(kf1, qf[1][k], sacc[1][1], 0, 0, 0);
      short8 vf0 = *(const short8*)(vbp + (2 * k) * 1024 + lane16);
      short8 vf1 = *(const short8*)(vbp + (2 * k + 1) * 1024 + lane16);
      yacc[0][2 * k] = __builtin_amdgcn_mfma_f32_16x16x32_bf16(a0, vf0, yacc[0][2 * k], 0, 0, 0);
      yacc[1][2 * k] = __builtin_amdgcn_mfma_f32_16x16x32_bf16(a1, vf0, yacc[1][2 * k], 0, 0, 0);
      yacc[0][2 * k + 1] = __builtin_amdgcn_mfma_f32_16x16x32_bf16(a0, vf1, yacc[0][2 * k + 1], 0, 0, 0);
      yacc[1][2 * k + 1] = __builtin_amdgcn_mfma_f32_16x16x32_bf16(a1, vf1, yacc[1][2 * k + 1], 0, 0, 0);
    }
    __builtin_amdgcn_s_setprio(0);

#pragma unroll
    for (int mt = 0; mt < 2; ++mt)
#pragma unroll
      for (int n0 = 0; n0 < 2; ++n0)
#pragma unroll
        for (int h = 0; h < 2; ++h) {
          float a2 = fmaxf(sacc[n0][mt][2 * h], 0.f); a2 *= a2;
          float a3 = fmaxf(sacc[n0][mt][2 * h + 1], 0.f); a3 *= a3;
          u32 w;
          asm("v_cvt_pk_bf16_f32 %0, %1, %2" : "=v"(w) : "v"(a2), "v"(a3));
          pa[mt][n0 * 2 + h] = w;
        }
  }

  // ---- tail: PV(ntiles-1)
  asm volatile("s_waitcnt vmcnt(0)" ::: "memory");
  __builtin_amdgcn_s_barrier();
  {
    const char* vbl = smem + ((ntiles - 1) % 3) * 32768 + 16384;
    u32x4 w0 = {pa[0][0], pa[0][1], pa[0][2], pa[0][3]};
    u32x4 w1 = {pa[1][0], pa[1][1], pa[1][2], pa[1][3]};
    short8 a0 = __builtin_bit_cast(short8, w0);
    short8 a1 = __builtin_bit_cast(short8, w1);
    __builtin_amdgcn_s_setprio(1);
#pragma unroll
    for (int n2 = 0; n2 < 16; ++n2) {
      short8 vf = *(const short8*)(vbl + n2 * 1024 + lane16);
      yacc[0][n2] = __builtin_amdgcn_mfma_f32_16x16x32_bf16(a0, vf, yacc[0][n2], 0, 0, 0);
      yacc[1][n2] = __builtin_amdgcn_mfma_f32_16x16x32_bf16(a1, vf, yacc[1][n2], 0, 0, 0);
    }
    __builtin_amdgcn_s_setprio(0);
  }
  __builtin_amdgcn_s_barrier();

  // ---- epilogue: per-wave LDS transpose for coalesced [c][p] stores
  // yacc[mt][n2][i] = y[p = p0 + mt*16 + g*4+i][c = n2*16 + lr]
  float* yl = (float*)(smem + wave * 12288);
  const int row8 = lane >> 3, p4 = (lane & 7) << 2;
#pragma unroll
  for (int cc = 0; cc < 4; ++cc) {
#pragma unroll
    for (int nn = 0; nn < 4; ++nn)
#pragma unroll
      for (int mt = 0; mt < 2; ++mt)
#pragma unroll
        for (int i = 0; i < 4; ++i)
          yl[(nn * 16 + lr) * 33 + mt * 16 + g * 4 + i] = yacc[mt][cc * 4 + nn][i];
#pragma unroll
    for (int r2 = 0; r2 < 8; ++r2) {
      int c = r2 * 8 + row8;
      float4 v = *(const float4*)(yl + c * 33 + p4);
      size_t off = ((size_t)b * CN + cc * 64 + c) * PN + p0 + p4;
      if (qs == 0) {
        *(float4*)(out + off) = v;
      } else {
        us4 h;
        h[0] = __builtin_bit_cast(unsigned short, __float2half(v.x));
        h[1] = __builtin_bit_cast(unsigned short, __float2half(v.y));
        h[2] = __builtin_bit_cast(unsigned short, __float2half(v.z));
        h[3] = __builtin_bit_cast(unsigned short, __float2half(v.w));
        *(us4*)(dsth + off) = h;
      }
    }
  }
}

// ---- final reduction: out += sum of f16 partials
__global__ void k_add(float* __restrict__ o, const unsigned int* __restrict__ a,
                      const unsigned int* __restrict__ bb, const unsigned int* __restrict__ c,
                      int np, int n4) {
  int i = blockIdx.x * blockDim.x + threadIdx.x;
  int stride = gridDim.x * blockDim.x;
  float4* o4 = (float4*)o;
  const uint2* a2 = (const uint2*)a;
  const uint2* b2 = (const uint2*)bb;
  const uint2* c2 = (const uint2*)c;
  for (; i < n4; i += stride) {
    float4 r = o4[i];
    uint2 ua = a2[i];
    float2 f0 = __half22float2(__builtin_bit_cast(__half2, ua.x));
    float2 f1 = __half22float2(__builtin_bit_cast(__half2, ua.y));
    r.x += f0.x; r.y += f0.y; r.z += f1.x; r.w += f1.y;
    if (np > 1) {
      uint2 ub = b2[i];
      f0 = __half22float2(__builtin_bit_cast(__half2, ub.x));
      f1 = __half22float2(__builtin_bit_cast(__half2, ub.y));
      r.x += f0.x; r.y += f0.y; r.z += f1.x; r.w += f1.y;
      uint2 uc = c2[i];
      f0 = __half22float2(__builtin_bit_cast(__half2, uc.x));
      f1 = __half22float2(__builtin_bit_cast(__half2, uc.y));
      r.x += f0.x; r.y += f0.y; r.z += f1.x; r.w += f1.y;
    }
    o4[i] = r;
  }
}

extern "C" void kernel_launch(void* const* d_in, const int* in_sizes, int n_in,
                              void* d_out, int out_size, void* d_ws, size_t ws_size,
                              hipStream_t stream) {
  const float* x = (const float*)d_in[0];
  const float* Wm = (const float*)d_in[1];
  const float* bias = (const float*)d_in[2];
  float* out = (float*)d_out;

  char* ws = (char*)d_ws;
  unsigned short* xnK = (unsigned short*)ws;                        // 8 MB  frag-major xn
  unsigned short* gxF = (unsigned short*)(ws + (size_t)8388608);    // 8 MB  frag-major permuted V
  float* mnorm = (float*)(ws + (size_t)16777216);                   // 64 KB [B][P] f32
  __half* p1 = (__half*)(ws + (size_t)16842752);                    // 8 MB f16 partials x3
  __half* p2 = p1 + 4194304;
  __half* p3 = p2 + 4194304;
  const size_t need4 = 16842752ULL + 3ULL * 8388608ULL;

  hipFuncSetAttribute(reinterpret_cast<const void*>(k_attn),
                      hipFuncAttributeMaxDynamicSharedMemorySize, 98304);

  k_nx<<<dim3(PN / 64, BN), 256, 0, stream>>>(x, mnorm, xnK);
  k_gx<<<dim3(PN / 64, CN / 64, BN), 256, 0, stream>>>(Wm, bias, xnK, mnorm, gxF);
  if (ws_size >= need4) {
    k_attn<<<dim3(256), 512, 98304, stream>>>(xnK, gxF, out, p1, p2, p3, 2, (PN / 4) / QT);
    k_add<<<dim3(1024), 256, 0, stream>>>(out, (const unsigned int*)p1, (const unsigned int*)p2,
                                          (const unsigned int*)p3, 3, BN * CN * PN / 4);
  } else {
    k_attn<<<dim3(128), 512, 98304, stream>>>(xnK, gxF, out, p1, p1, p1, 1, (PN / 2) / QT);
    k_add<<<dim3(1024), 256, 0, stream>>>(out, (const unsigned int*)p1, (const unsigned int*)p1,
                                          (const unsigned int*)p1, 1, BN * CN * PN / 4);
  }
}

// Round 12
// 94.673 us; speedup vs baseline: 1.1076x; 1.1013x over previous
//
#include <hip/hip_runtime.h>
#include <hip/hip_fp16.h>

#define BN 4
#define CN 256
#define PN 4096
#define QT 64
#define TSTR 264

typedef __attribute__((ext_vector_type(8))) short short8;
typedef __attribute__((ext_vector_type(8))) unsigned short ushort8;
typedef __attribute__((ext_vector_type(4))) unsigned short us4;
typedef __attribute__((ext_vector_type(4))) float f32x4;
typedef __attribute__((ext_vector_type(4))) unsigned int u32x4;
typedef unsigned int u32;

__device__ __forceinline__ unsigned short f2bf(float f) {
  u32 u = __builtin_bit_cast(u32, f);
  return (unsigned short)((u + 0x7fffu + ((u >> 16) & 1u)) >> 16);
}

__device__ __forceinline__ void async_copy16(const void* g, void* l) {
  __builtin_amdgcn_global_load_lds((const __attribute__((address_space(1))) u32*)g,
                                   (__attribute__((address_space(3))) u32*)l, 16, 0, 0);
}

// Frag-major layout (per batch, per 64-q block = 32 KB = 32 frags of 1024B):
//   frag F = nt*8 + kc; byte = F*1024 + (g*16+lr)*16 + j*2
//     <-> xn[q = qb*64 + nt*16 + lr][ch = kc*32 + g*8 + j]
// V frags q-PERMUTED: frag f = kk*16 + n2; byte = f*1024 + (g*16+lr)*16 + j*2
//     <-> V[q = kk*32 + perm(g*8+j)][c = n2*16 + lr]  (perm matches cvt_pk'd S order)

// ---- fused k_nxgx: norms + xnK (frag-major bf16) + gxF (frag-major permuted V)
__global__ __launch_bounds__(256) void k_nxgx(const float* __restrict__ x,
                                              const float* __restrict__ Wm,
                                              const float* __restrict__ bias,
                                              unsigned short* __restrict__ xnK,
                                              unsigned short* __restrict__ gxF) {
  __shared__ unsigned short tl[64 * TSTR];
  __shared__ float red[4][64];
  __shared__ float mnl[64];
  const int b = blockIdx.y, qb = blockIdx.x, p0 = qb * 64;
  const int tid = threadIdx.x;
  const int tp = tid & 63, cg = tid >> 6;

  // ---- phase A: load x column-block, norms, bf16 transpose into tl
  {
    const float* xp = x + ((size_t)b * CN + cg * 64) * PN + p0 + tp;
    float v[64];
    float ss = 0.f;
#pragma unroll
    for (int i = 0; i < 64; ++i) {
      v[i] = xp[(size_t)i * PN];
      ss += v[i] * v[i];
    }
    red[cg][tp] = ss;
    __syncthreads();
    float nrm = sqrtf(red[0][tp] + red[1][tp] + red[2][tp] + red[3][tp]);
    float mn = fmaxf(nrm, 1e-8f);
    float rn = 1.f / mn;
    if (cg == 0) mnl[tp] = mn;
    unsigned int* tl32 = (unsigned int*)tl;
#pragma unroll
    for (int j = 0; j < 32; ++j) {
      unsigned int w = (unsigned int)f2bf(v[2 * j] * rn) |
                       ((unsigned int)f2bf(v[2 * j + 1] * rn) << 16);
      tl32[tp * (TSTR / 2) + cg * 32 + j] = w;
    }
    __syncthreads();
    // frag-major store of xn to global
    char* dstb = (char*)xnK + (size_t)b * (PN * CN * 2) + (size_t)qb * 32768;
#pragma unroll
    for (int m = 0; m < 8; ++m) {
      int idx = m * 256 + tid;
      int F = idx >> 6, ln = idx & 63;
      int pl = (F >> 3) * 16 + (ln & 15);
      int ch = (F & 7) * 32 + (ln >> 4) * 8;
      ushort8 o = *(const ushort8*)(tl + pl * TSTR + ch);
      *(ushort8*)(dstb + (size_t)idx * 16) = o;
    }
  }

  // ---- phase B: gx = (W @ xn)*mn + bias, scattered to permuted V-frag layout
  const int wave = tid >> 6, lane = tid & 63;
  const int lr = lane & 15, g = lane >> 4;
  char* vbb = (char*)gxF + (size_t)b * (PN * CN * 2) + (size_t)qb * 32768;
#pragma unroll
  for (int mp = 0; mp < 2; ++mp) {
    short8 af[2][8];
#pragma unroll
    for (int mt = 0; mt < 2; ++mt) {
      const float* wr = Wm + (size_t)(wave * 64 + mp * 32 + mt * 16 + lr) * CN;
#pragma unroll
      for (int k = 0; k < 8; ++k) {
        const float* ap = wr + k * 32 + g * 8;
        short8 a;
#pragma unroll
        for (int j = 0; j < 8; ++j) a[j] = (short)f2bf(ap[j]);
        af[mt][k] = a;
      }
    }
    f32x4 acc[2][4];
#pragma unroll
    for (int mt = 0; mt < 2; ++mt)
#pragma unroll
      for (int n = 0; n < 4; ++n) acc[mt][n] = (f32x4){0.f, 0.f, 0.f, 0.f};
#pragma unroll
    for (int n = 0; n < 4; ++n)
#pragma unroll
      for (int k = 0; k < 8; ++k) {
        short8 bf = *(const short8*)((const char*)tl + (n * 16 + lr) * (TSTR * 2) + k * 64 + g * 16);
        acc[0][n] = __builtin_amdgcn_mfma_f32_16x16x32_bf16(af[0][k], bf, acc[0][n], 0, 0, 0);
        acc[1][n] = __builtin_amdgcn_mfma_f32_16x16x32_bf16(af[1][k], bf, acc[1][n], 0, 0, 0);
      }
#pragma unroll
    for (int n = 0; n < 4; ++n) {
      float mn = mnl[n * 16 + lr];
      int kk = n >> 1;
      int q32 = (n & 1) * 16 + lr;
      int gp = (q32 >> 2) & 3;
      int j = ((q32 >> 4) & 1) * 4 + (q32 & 3);
#pragma unroll
      for (int mt = 0; mt < 2; ++mt)
#pragma unroll
        for (int i = 0; i < 4; ++i) {
          int c = wave * 64 + mp * 32 + mt * 16 + g * 4 + i;
          float v = acc[mt][n][i] * mn + bias[c];
          *(unsigned short*)(vbb + ((kk * 16 + (c >> 4)) << 10) + (gp << 8) + ((c & 15) << 4) + (j << 1)) = f2bf(v);
        }
    }
  }
}

// ---- fused attention: r9's proven loop (8-wave WG, M=32/wave, QT=64, 128KB dbuf,
// counted vmcnt(4)/(8), in-register q-permuted S). Epilogue: f16 partials.
extern __shared__ char smem[];

__global__ __launch_bounds__(512, 2) void k_attn(const unsigned short* __restrict__ xnK,
                                                 const unsigned short* __restrict__ gxF,
                                                 __half* __restrict__ p0h, __half* __restrict__ p1h,
                                                 __half* __restrict__ p2h, __half* __restrict__ p3h,
                                                 int lq, int ntiles) {
  const int fid = blockIdx.x;
  const int b = fid & 3;
  const int qs = (fid >> 2) & ((1 << lq) - 1);
  const int pblk = fid >> (2 + lq);
  const int tid = threadIdx.x;
  const int wave = tid >> 6, lane = tid & 63, lr = lane & 15, g = lane >> 4;
  const int qb0 = (qs * (PN >> lq)) >> 6;
  const int p0 = pblk * 256 + wave * 32;
  __half* dsth = (qs == 0) ? p0h : (qs == 1) ? p1h : (qs == 2) ? p2h : p3h;

  const char* xb = (const char*)xnK + (size_t)b * (PN * CN * 2);
  const char* vg = (const char*)gxF + (size_t)b * (PN * CN * 2);
  const char* kq = xb + (size_t)qb0 * 32768;
  const char* vq = vg + (size_t)qb0 * 32768;
  const int ldst = tid * 16;
  const int lane16 = lane * 16;

  auto issue_K = [&](int t) {
    char* kb = smem + (t & 1) * 65536;
    const char* s = kq + (size_t)t * 32768 + ldst;
#pragma unroll
    for (int j = 0; j < 4; ++j) async_copy16(s + j * 8192, kb + ldst + j * 8192);
  };
  auto issue_V = [&](int t) {
    char* vb = smem + (t & 1) * 65536 + 32768;
    const char* s = vq + (size_t)t * 32768 + ldst;
#pragma unroll
    for (int j = 0; j < 4; ++j) async_copy16(s + j * 8192, vb + ldst + j * 8192);
  };

  issue_K(0);
  issue_V(0);

  // Q hoist (32 p-rows x 256 ch as B-operand frags)
  short8 qf[2][8];
  {
    const char* qpb = xb + (size_t)(pblk * 4 + (wave >> 1)) * 32768;
#pragma unroll
    for (int mt = 0; mt < 2; ++mt) {
      int ntp = (wave & 1) * 2 + mt;
#pragma unroll
      for (int k = 0; k < 8; ++k)
        qf[mt][k] = *(const short8*)(qpb + ((ntp * 8 + k) << 10) + ((g * 16 + lr) << 4));
    }
  }

  f32x4 yacc[2][16];
#pragma unroll
  for (int mt = 0; mt < 2; ++mt)
#pragma unroll
    for (int n = 0; n < 16; ++n) yacc[mt][n] = (f32x4){0.f, 0.f, 0.f, 0.f};

  for (int t = 0; t < ntiles; ++t) {
    const char* kb = smem + (t & 1) * 65536;
    const char* vb = kb + 32768;

    asm volatile("s_waitcnt vmcnt(4)" ::: "memory");  // K(t) ready (V(t) in flight)
    __builtin_amdgcn_s_barrier();
    if (t + 1 < ntiles) { issue_K(t + 1); issue_V(t + 1); }

    // QKT (swapped: D[q][p] = mfma(K, Q)) + in-register S pack (q-permuted)
    u32 pa[2][2][4];  // [mt][kk][word]
#pragma unroll
    for (int nh = 0; nh < 2; ++nh) {
      f32x4 sacc[2][2];
#pragma unroll
      for (int n0 = 0; n0 < 2; ++n0)
#pragma unroll
        for (int mt = 0; mt < 2; ++mt) sacc[n0][mt] = (f32x4){0.f, 0.f, 0.f, 0.f};
      __builtin_amdgcn_s_setprio(1);
#pragma unroll
      for (int k = 0; k < 8; ++k) {
        short8 kf0 = *(const short8*)(kb + ((2 * nh) * 8 + k) * 1024 + lane16);
        short8 kf1 = *(const short8*)(kb + ((2 * nh + 1) * 8 + k) * 1024 + lane16);
        sacc[0][0] = __builtin_amdgcn_mfma_f32_16x16x32_bf16(kf0, qf[0][k], sacc[0][0], 0, 0, 0);
        sacc[0][1] = __builtin_amdgcn_mfma_f32_16x16x32_bf16(kf0, qf[1][k], sacc[0][1], 0, 0, 0);
        sacc[1][0] = __builtin_amdgcn_mfma_f32_16x16x32_bf16(kf1, qf[0][k], sacc[1][0], 0, 0, 0);
        sacc[1][1] = __builtin_amdgcn_mfma_f32_16x16x32_bf16(kf1, qf[1][k], sacc[1][1], 0, 0, 0);
      }
      __builtin_amdgcn_s_setprio(0);
#pragma unroll
      for (int mt = 0; mt < 2; ++mt)
#pragma unroll
        for (int n0 = 0; n0 < 2; ++n0)
#pragma unroll
          for (int h = 0; h < 2; ++h) {
            float a0 = fmaxf(sacc[n0][mt][2 * h], 0.f); a0 *= a0;
            float a1 = fmaxf(sacc[n0][mt][2 * h + 1], 0.f); a1 *= a1;
            u32 w;
            asm("v_cvt_pk_bf16_f32 %0, %1, %2" : "=v"(w) : "v"(a0), "v"(a1));
            pa[mt][nh][n0 * 2 + h] = w;
          }
    }

    if (t + 1 < ntiles) {
      asm volatile("s_waitcnt vmcnt(8)" ::: "memory");  // V(t) ready (t+1 in flight)
    } else {
      asm volatile("s_waitcnt vmcnt(0)" ::: "memory");
    }
    __builtin_amdgcn_s_barrier();

    // PV: Y[32p][256c] += S @ V (shared q-permutation)
#pragma unroll
    for (int kk = 0; kk < 2; ++kk) {
      u32x4 w0 = {pa[0][kk][0], pa[0][kk][1], pa[0][kk][2], pa[0][kk][3]};
      u32x4 w1 = {pa[1][kk][0], pa[1][kk][1], pa[1][kk][2], pa[1][kk][3]};
      short8 a0 = __builtin_bit_cast(short8, w0);
      short8 a1 = __builtin_bit_cast(short8, w1);
      __builtin_amdgcn_s_setprio(1);
#pragma unroll
      for (int n2 = 0; n2 < 16; ++n2) {
        short8 vf = *(const short8*)(vb + (kk * 16 + n2) * 1024 + lane16);
        yacc[0][n2] = __builtin_amdgcn_mfma_f32_16x16x32_bf16(a0, vf, yacc[0][n2], 0, 0, 0);
        yacc[1][n2] = __builtin_amdgcn_mfma_f32_16x16x32_bf16(a1, vf, yacc[1][n2], 0, 0, 0);
      }
      __builtin_amdgcn_s_setprio(0);
    }
  }
  __builtin_amdgcn_s_barrier();

  // ---- epilogue: per-wave LDS transpose, f16 partial stores
  // yacc[mt][n2][i] = y[p = p0 + mt*16 + g*4+i][c = n2*16 + lr]
  float* yl = (float*)(smem + wave * 16384);
  const int row8 = lane >> 3, p4 = (lane & 7) << 2;
#pragma unroll
  for (int cc = 0; cc < 4; ++cc) {
#pragma unroll
    for (int nn = 0; nn < 4; ++nn)
#pragma unroll
      for (int mt = 0; mt < 2; ++mt)
#pragma unroll
        for (int i = 0; i < 4; ++i)
          yl[(nn * 16 + lr) * 33 + mt * 16 + g * 4 + i] = yacc[mt][cc * 4 + nn][i];
#pragma unroll
    for (int r2 = 0; r2 < 8; ++r2) {
      int c = r2 * 8 + row8;
      float4 v = *(const float4*)(yl + c * 33 + p4);
      size_t off = ((size_t)b * CN + cc * 64 + c) * PN + p0 + p4;
      us4 h;
      h[0] = __builtin_bit_cast(unsigned short, __float2half(v.x));
      h[1] = __builtin_bit_cast(unsigned short, __float2half(v.y));
      h[2] = __builtin_bit_cast(unsigned short, __float2half(v.z));
      h[3] = __builtin_bit_cast(unsigned short, __float2half(v.w));
      *(us4*)(dsth + off) = h;
    }
  }
}

// ---- final reduction: out = sum of np f16 partials
__global__ void k_add(float* __restrict__ o, const uint2* __restrict__ a,
                      const uint2* __restrict__ bb, const uint2* __restrict__ c,
                      const uint2* __restrict__ d, int np, int n4) {
  int i = blockIdx.x * blockDim.x + threadIdx.x;
  int stride = gridDim.x * blockDim.x;
  float4* o4 = (float4*)o;
  for (; i < n4; i += stride) {
    uint2 ua = a[i];
    float2 f0 = __half22float2(__builtin_bit_cast(__half2, ua.x));
    float2 f1 = __half22float2(__builtin_bit_cast(__half2, ua.y));
    float4 r = {f0.x, f0.y, f1.x, f1.y};
    uint2 ub = bb[i];
    f0 = __half22float2(__builtin_bit_cast(__half2, ub.x));
    f1 = __half22float2(__builtin_bit_cast(__half2, ub.y));
    r.x += f0.x; r.y += f0.y; r.z += f1.x; r.w += f1.y;
    if (np > 2) {
      uint2 uc = c[i];
      f0 = __half22float2(__builtin_bit_cast(__half2, uc.x));
      f1 = __half22float2(__builtin_bit_cast(__half2, uc.y));
      r.x += f0.x; r.y += f0.y; r.z += f1.x; r.w += f1.y;
      uint2 ud = d[i];
      f0 = __half22float2(__builtin_bit_cast(__half2, ud.x));
      f1 = __half22float2(__builtin_bit_cast(__half2, ud.y));
      r.x += f0.x; r.y += f0.y; r.z += f1.x; r.w += f1.y;
    }
    o4[i] = r;
  }
}

extern "C" void kernel_launch(void* const* d_in, const int* in_sizes, int n_in,
                              void* d_out, int out_size, void* d_ws, size_t ws_size,
                              hipStream_t stream) {
  const float* x = (const float*)d_in[0];
  const float* Wm = (const float*)d_in[1];
  const float* bias = (const float*)d_in[2];
  float* out = (float*)d_out;

  char* ws = (char*)d_ws;
  unsigned short* xnK = (unsigned short*)ws;                        // 8 MB frag-major xn
  unsigned short* gxF = (unsigned short*)(ws + (size_t)8388608);    // 8 MB frag-major permuted V
  __half* p0 = (__half*)(ws + (size_t)16777216);                    // f16 partials x4 (8 MB each)
  __half* p1 = p0 + 4194304;
  __half* p2 = p1 + 4194304;
  __half* p3 = p2 + 4194304;
  const size_t need4 = 16777216ULL + 4ULL * 8388608ULL;

  hipFuncSetAttribute(reinterpret_cast<const void*>(k_attn),
                      hipFuncAttributeMaxDynamicSharedMemorySize, 131072);

  k_nxgx<<<dim3(PN / 64, BN), 256, 0, stream>>>(x, Wm, bias, xnK, gxF);
  if (ws_size >= need4) {
    k_attn<<<dim3(256), 512, 131072, stream>>>(xnK, gxF, p0, p1, p2, p3, 2, (PN / 4) / QT);
    k_add<<<dim3(1024), 256, 0, stream>>>(out, (const uint2*)p0, (const uint2*)p1,
                                          (const uint2*)p2, (const uint2*)p3, 4, BN * CN * PN / 4);
  } else {
    k_attn<<<dim3(128), 512, 131072, stream>>>(xnK, gxF, p0, p1, p0, p1, 1, (PN / 2) / QT);
    k_add<<<dim3(1024), 256, 0, stream>>>(out, (const uint2*)p0, (const uint2*)p1,
                                          (const uint2*)p0, (const uint2*)p1, 2, BN * CN * PN / 4);
  }
}